// Round 1
// 2826.984 us; speedup vs baseline: 8.5523x; 8.5523x over previous
//
#include <hip/hip_runtime.h>

// ---------------------------------------------------------------------------
// VQ-VAE encoder: 4x [conv k=4 s=2 p=1 + ReLU] then nearest-codebook lookup.
// This round: tiled LDS conv (64co x 8x16 spatial per block, 4co x 8wo per
// thread register tile) to convert latency-bound direct conv into
// VALU-bound implicit GEMM. VQ path unchanged.
// ---------------------------------------------------------------------------

#define THREADS 256

// Tiled direct conv, NCHW/OIHW, k=4, stride=2, pad=1, fused bias+ReLU.
// Block: TC=64 output channels x (TH=8 x TW=16) output tile, one batch image.
// Thread: 4 co x 8 consecutive wo. CIN processed in chunks of KC via LDS.
template<int CIN, int KC>
__global__ __launch_bounds__(THREADS)
void conv_tiled_kernel(const float* __restrict__ x, const float* __restrict__ w,
                       const float* __restrict__ bias, float* __restrict__ y,
                       int B, int Cout, int Hin, int Win,
                       int nCt, int nHt, int nWt) {
    constexpr int TH = 8, TW = 16, TC = 64;
    constexpr int XR = 2 * TH + 2;      // 18 input rows per tile
    constexpr int XC = 2 * TW + 2;      // 34 real input cols
    constexpr int ROWP = 36;            // padded row (144B, 16B-aligned)
    constexpr int XTOT = KC * XR * ROWP;
    constexpr int WTOT = TC * KC * 16;

    __shared__ float xs[KC][XR][ROWP];  // staged input patch
    __shared__ float ws[TC][KC][16];    // staged weight slice

    const int Ho = Hin >> 1, Wo = Win >> 1;

    int id = blockIdx.x;
    const int wt = id % nWt; id /= nWt;
    const int ht = id % nHt; id /= nHt;
    const int ct = id % nCt; const int b = id / nCt;

    const int oh0 = ht * TH, ow0 = wt * TW, co0 = ct * TC;
    const int h0 = 2 * oh0 - 1;         // input row of patch row 0
    const int w0 = 2 * ow0 - 1;         // input col of patch col 0

    const int tid  = threadIdx.x;
    const int co_l = (tid >> 4) * 4;    // 16 groups of 4 channels
    const int sp   = tid & 15;
    const int lho  = sp >> 1;           // 0..7
    const int lwo  = (sp & 1) * 8;      // 0 or 8

    float acc[4][8];
    #pragma unroll
    for (int co = 0; co < 4; ++co) {
        const float bv = bias[co0 + co_l + co];
        #pragma unroll
        for (int j = 0; j < 8; ++j) acc[co][j] = bv;
    }

    float* __restrict__ xs_f = &xs[0][0][0];
    float* __restrict__ ws_f = &ws[0][0][0];

    for (int cc = 0; cc < CIN / KC; ++cc) {
        const int ci0 = cc * KC;

        // ---- stage input patch (zero-filled borders), coalesced rows ----
        for (int j = tid; j < XTOT; j += THREADS) {
            const int ci = j / (XR * ROWP);
            const int rr = (j - ci * (XR * ROWP)) / ROWP;
            const int c  = j % ROWP;
            const int hi = h0 + rr;
            const int wi = w0 + c;
            float v = 0.0f;
            if (c < XC && (unsigned)hi < (unsigned)Hin && (unsigned)wi < (unsigned)Win)
                v = x[((b * CIN + ci0 + ci) * Hin + hi) * Win + wi];
            xs_f[j] = v;
        }
        // ---- stage weight slice: ws[co][ci][k] <- w[co0+co][ci0+ci][k] ----
        // per-co chunk of KC*16 floats is contiguous in global memory
        for (int j = tid; j < WTOT; j += THREADS) {
            const int co  = j / (KC * 16);
            const int rem = j - co * (KC * 16);
            ws_f[j] = w[((co0 + co) * CIN + ci0) * 16 + rem];
        }
        __syncthreads();

        // ---- compute: 512 fma per ci per thread ----
        #pragma unroll 1
        for (int ci = 0; ci < KC; ++ci) {
            #pragma unroll
            for (int kh = 0; kh < 4; ++kh) {
                const float* __restrict__ xr = &xs[ci][2 * lho + kh][2 * lwo];
                const float4 a0 = *(const float4*)(xr + 0);
                const float4 a1 = *(const float4*)(xr + 4);
                const float4 a2 = *(const float4*)(xr + 8);
                const float4 a3 = *(const float4*)(xr + 12);
                const float4 a4 = *(const float4*)(xr + 16);
                const float xf[20] = {a0.x, a0.y, a0.z, a0.w,
                                      a1.x, a1.y, a1.z, a1.w,
                                      a2.x, a2.y, a2.z, a2.w,
                                      a3.x, a3.y, a3.z, a3.w,
                                      a4.x, a4.y, a4.z, a4.w};
                #pragma unroll
                for (int co = 0; co < 4; ++co) {
                    const float4 wv = *(const float4*)&ws[co_l + co][ci][kh * 4];
                    #pragma unroll
                    for (int j = 0; j < 8; ++j) {
                        acc[co][j] = fmaf(xf[2 * j + 0], wv.x, acc[co][j]);
                        acc[co][j] = fmaf(xf[2 * j + 1], wv.y, acc[co][j]);
                        acc[co][j] = fmaf(xf[2 * j + 2], wv.z, acc[co][j]);
                        acc[co][j] = fmaf(xf[2 * j + 3], wv.w, acc[co][j]);
                    }
                }
            }
        }
        __syncthreads();
    }

    // ---- epilogue: ReLU + vectorized store ----
    #pragma unroll
    for (int co = 0; co < 4; ++co) {
        float* __restrict__ yp =
            &y[((b * Cout + co0 + co_l + co) * Ho + oh0 + lho) * Wo + ow0 + lwo];
        float4 r0, r1;
        r0.x = fmaxf(acc[co][0], 0.0f);
        r0.y = fmaxf(acc[co][1], 0.0f);
        r0.z = fmaxf(acc[co][2], 0.0f);
        r0.w = fmaxf(acc[co][3], 0.0f);
        r1.x = fmaxf(acc[co][4], 0.0f);
        r1.y = fmaxf(acc[co][5], 0.0f);
        r1.z = fmaxf(acc[co][6], 0.0f);
        r1.w = fmaxf(acc[co][7], 0.0f);
        *(float4*)yp       = r0;
        *(float4*)(yp + 4) = r1;
    }
}

// codebook row squared norms
__global__ __launch_bounds__(THREADS)
void cnorm_kernel(const float* __restrict__ cb, float* __restrict__ cn) {
    int c = blockIdx.x * THREADS + threadIdx.x;   // 8192 rows
    const float* __restrict__ row = cb + c * 256;
    float s = 0.0f;
    for (int k = 0; k < 256; k += 4) {
        float4 v = *(const float4*)(row + k);
        s = fmaf(v.x, v.x, s);
        s = fmaf(v.y, v.y, s);
        s = fmaf(v.z, v.z, s);
        s = fmaf(v.w, v.w, s);
    }
    cn[c] = s;
}

// Fused VQ argmin. Block handles VQ_Q query vectors; each thread owns the
// code set {t, t+256, ...} and keeps a per-query running (best, idx).
// z4 layout: NCHW (b, c, 16, 16); query n = b*256 + h*16 + w.
#define VQ_Q 16
__global__ __launch_bounds__(THREADS)
void vq_argmin_kernel(const float* __restrict__ z, const float* __restrict__ cb,
                      const float* __restrict__ cnorm, int* __restrict__ idx) {
    __shared__ float zf[256][VQ_Q];     // [k][q], 16 KB, broadcast reads
    __shared__ float rbd[VQ_Q][256];    // reduction scratch
    __shared__ int   rbi[VQ_Q][256];

    const int t  = threadIdx.x;
    const int q0 = blockIdx.x * VQ_Q;

    // stage queries: thread t loads channel k=t for each query
    for (int q = 0; q < VQ_Q; ++q) {
        int n  = q0 + q;
        int b  = n >> 8;
        int hw = n & 255;
        zf[t][q] = z[(b * 256 + t) * 256 + hw];
    }
    __syncthreads();

    float bd[VQ_Q];
    int   bi[VQ_Q];
    #pragma unroll
    for (int q = 0; q < VQ_Q; ++q) { bd[q] = 3.4e38f; bi[q] = 0; }

    for (int c = t; c < 8192; c += THREADS) {
        const float* __restrict__ crow = cb + c * 256;
        float acc[VQ_Q];
        #pragma unroll
        for (int q = 0; q < VQ_Q; ++q) acc[q] = 0.0f;

        for (int k = 0; k < 256; k += 4) {
            float4 cv = *(const float4*)(crow + k);
            #pragma unroll
            for (int kk = 0; kk < 4; ++kk) {
                float ck = (kk == 0) ? cv.x : (kk == 1) ? cv.y : (kk == 2) ? cv.z : cv.w;
                #pragma unroll
                for (int q = 0; q < VQ_Q; q += 4) {
                    float4 zv = *(const float4*)&zf[k + kk][q];
                    acc[q + 0] = fmaf(ck, zv.x, acc[q + 0]);
                    acc[q + 1] = fmaf(ck, zv.y, acc[q + 1]);
                    acc[q + 2] = fmaf(ck, zv.z, acc[q + 2]);
                    acc[q + 3] = fmaf(ck, zv.w, acc[q + 3]);
                }
            }
        }
        float cn = cnorm[c];
        #pragma unroll
        for (int q = 0; q < VQ_Q; ++q) {
            float d = fmaf(-2.0f, acc[q], cn);   // ||c||^2 - 2 z.c  (argmin-equivalent)
            if (d < bd[q]) { bd[q] = d; bi[q] = c; }
        }
    }

    #pragma unroll
    for (int q = 0; q < VQ_Q; ++q) { rbd[q][t] = bd[q]; rbi[q][t] = bi[q]; }
    __syncthreads();

    // first-min tie-break: lexicographic (d, idx)
    if (t < VQ_Q) {
        float best = 3.4e38f; int besti = 0;
        for (int j = 0; j < THREADS; ++j) {
            float d = rbd[t][j]; int ci = rbi[t][j];
            if (d < best || (d == best && ci < besti)) { best = d; besti = ci; }
        }
        idx[q0 + t] = besti;
    }
}

// Epilogue: out[0:2097152] = codebook[idx] in NCHW; out[2097152:] = (float)idx.
__global__ __launch_bounds__(THREADS)
void gather_kernel(const float* __restrict__ cb, const int* __restrict__ idx,
                   float* __restrict__ out) {
    int i = blockIdx.x * THREADS + threadIdx.x;
    if (i < 32 * 256 * 16 * 16) {
        int w = i & 15;
        int h = (i >> 4) & 15;
        int c = (i >> 8) & 255;
        int b = i >> 16;
        int n = (b << 8) | (h << 4) | w;
        out[i] = cb[idx[n] * 256 + c];
    }
    if (i < 8192) {
        out[32 * 256 * 16 * 16 + i] = (float)idx[i];
    }
}

extern "C" void kernel_launch(void* const* d_in, const int* in_sizes, int n_in,
                              void* d_out, int out_size, void* d_ws, size_t ws_size,
                              hipStream_t stream) {
    const float* x  = (const float*)d_in[0];
    const float* w1 = (const float*)d_in[1];
    const float* b1 = (const float*)d_in[2];
    const float* w2 = (const float*)d_in[3];
    const float* b2 = (const float*)d_in[4];
    const float* w3 = (const float*)d_in[5];
    const float* b3 = (const float*)d_in[6];
    const float* w4 = (const float*)d_in[7];
    const float* b4 = (const float*)d_in[8];
    const float* cb = (const float*)d_in[9];
    float* out = (float*)d_out;

    char* ws = (char*)d_ws;
    // z1: 32*64*128*128 f32 = 134217728 B @ 0
    // z2: 32*128*64*64  f32 =  67108864 B @ 134217728
    // z3: 32*256*32*32  f32 =  33554432 B @ 0          (reuse z1)
    // z4: 32*256*16*16  f32 =   8388608 B @ 134217728  (reuse z2)
    // cnorm: 8192 f32 @ 142606336 ; idx: 8192 i32 @ 142639104
    float* z1 = (float*)(ws);
    float* z2 = (float*)(ws + 134217728);
    float* z3 = (float*)(ws);
    float* z4 = (float*)(ws + 134217728);
    float* cn = (float*)(ws + 142606336);
    int*   ix = (int*)  (ws + 142639104);

    // conv1: (32,3,256,256) -> (32,64,128,128)   grid: 32 * 1ct * 16ht * 8wt
    conv_tiled_kernel<3, 3><<<32 * 1 * 16 * 8, THREADS, 0, stream>>>(
        x, w1, b1, z1, 32, 64, 256, 256, 1, 16, 8);
    // conv2: -> (32,128,64,64)                   grid: 32 * 2 * 8 * 4
    conv_tiled_kernel<64, 8><<<32 * 2 * 8 * 4, THREADS, 0, stream>>>(
        z1, w2, b2, z2, 32, 128, 128, 128, 2, 8, 4);
    // conv3: -> (32,256,32,32)                   grid: 32 * 4 * 4 * 2
    conv_tiled_kernel<128, 8><<<32 * 4 * 4 * 2, THREADS, 0, stream>>>(
        z2, w3, b3, z3, 32, 256, 64, 64, 4, 4, 2);
    // conv4: -> (32,256,16,16)                   grid: 32 * 4 * 2 * 1
    conv_tiled_kernel<256, 8><<<32 * 4 * 2 * 1, THREADS, 0, stream>>>(
        z3, w4, b4, z4, 32, 256, 32, 32, 4, 2, 1);

    // VQ
    cnorm_kernel<<<8192 / THREADS, THREADS, 0, stream>>>(cb, cn);
    vq_argmin_kernel<<<8192 / VQ_Q, THREADS, 0, stream>>>(z4, cb, cn, ix);

    // epilogue
    gather_kernel<<<(32 * 256 * 16 * 16) / THREADS, THREADS, 0, stream>>>(cb, ix, out);
}

// Round 2
// 2457.353 us; speedup vs baseline: 9.8388x; 1.1504x over previous
//
#include <hip/hip_runtime.h>

// ---------------------------------------------------------------------------
// VQ-VAE encoder: 4x [conv k=4 s=2 p=1 + ReLU] then nearest-codebook lookup.
// This round: (1) conv LDS chunk KC 8->4 (26.8KB/block -> ~16 waves/CU),
// (2) VQ rewritten as fp32 tiled GEMM: z-tile resident in LDS, codebook
// staged coalesced, 4q x 4c register tile, lexicographic shfl reduce +
// packed u64 atomicMin. Accumulation order identical to previous passing
// version -> bitwise-identical distances -> identical argmin.
// ---------------------------------------------------------------------------

#define THREADS 256

// Tiled direct conv, NCHW/OIHW, k=4, stride=2, pad=1, fused bias+ReLU.
// Block: TC=64 output channels x (TH=8 x TW=16) output tile, one batch image.
// Thread: 4 co x 8 consecutive wo. CIN processed in chunks of KC via LDS.
template<int CIN, int KC>
__global__ __launch_bounds__(THREADS)
void conv_tiled_kernel(const float* __restrict__ x, const float* __restrict__ w,
                       const float* __restrict__ bias, float* __restrict__ y,
                       int B, int Cout, int Hin, int Win,
                       int nCt, int nHt, int nWt) {
    constexpr int TH = 8, TW = 16, TC = 64;
    constexpr int XR = 2 * TH + 2;      // 18 input rows per tile
    constexpr int XC = 2 * TW + 2;      // 34 real input cols
    constexpr int ROWP = 36;            // padded row (144B, 16B-aligned)
    constexpr int XTOT = KC * XR * ROWP;
    constexpr int WTOT = TC * KC * 16;

    __shared__ float xs[KC][XR][ROWP];  // staged input patch
    __shared__ float ws[TC][KC][16];    // staged weight slice

    const int Ho = Hin >> 1, Wo = Win >> 1;

    int id = blockIdx.x;
    const int wt = id % nWt; id /= nWt;
    const int ht = id % nHt; id /= nHt;
    const int ct = id % nCt; const int b = id / nCt;

    const int oh0 = ht * TH, ow0 = wt * TW, co0 = ct * TC;
    const int h0 = 2 * oh0 - 1;         // input row of patch row 0
    const int w0 = 2 * ow0 - 1;         // input col of patch col 0

    const int tid  = threadIdx.x;
    const int co_l = (tid >> 4) * 4;    // 16 groups of 4 channels
    const int sp   = tid & 15;
    const int lho  = sp >> 1;           // 0..7
    const int lwo  = (sp & 1) * 8;      // 0 or 8

    float acc[4][8];
    #pragma unroll
    for (int co = 0; co < 4; ++co) {
        const float bv = bias[co0 + co_l + co];
        #pragma unroll
        for (int j = 0; j < 8; ++j) acc[co][j] = bv;
    }

    float* __restrict__ xs_f = &xs[0][0][0];
    float* __restrict__ ws_f = &ws[0][0][0];

    for (int cc = 0; cc < CIN / KC; ++cc) {
        const int ci0 = cc * KC;

        // ---- stage input patch (zero-filled borders), coalesced rows ----
        for (int j = tid; j < XTOT; j += THREADS) {
            const int ci = j / (XR * ROWP);
            const int rr = (j - ci * (XR * ROWP)) / ROWP;
            const int c  = j % ROWP;
            const int hi = h0 + rr;
            const int wi = w0 + c;
            float v = 0.0f;
            if (c < XC && (unsigned)hi < (unsigned)Hin && (unsigned)wi < (unsigned)Win)
                v = x[((b * CIN + ci0 + ci) * Hin + hi) * Win + wi];
            xs_f[j] = v;
        }
        // ---- stage weight slice: ws[co][ci][k] <- w[co0+co][ci0+ci][k] ----
        for (int j = tid; j < WTOT; j += THREADS) {
            const int co  = j / (KC * 16);
            const int rem = j - co * (KC * 16);
            ws_f[j] = w[((co0 + co) * CIN + ci0) * 16 + rem];
        }
        __syncthreads();

        // ---- compute: 512 fma per ci per thread ----
        #pragma unroll 1
        for (int ci = 0; ci < KC; ++ci) {
            #pragma unroll
            for (int kh = 0; kh < 4; ++kh) {
                const float* __restrict__ xr = &xs[ci][2 * lho + kh][2 * lwo];
                const float4 a0 = *(const float4*)(xr + 0);
                const float4 a1 = *(const float4*)(xr + 4);
                const float4 a2 = *(const float4*)(xr + 8);
                const float4 a3 = *(const float4*)(xr + 12);
                const float4 a4 = *(const float4*)(xr + 16);
                const float xf[20] = {a0.x, a0.y, a0.z, a0.w,
                                      a1.x, a1.y, a1.z, a1.w,
                                      a2.x, a2.y, a2.z, a2.w,
                                      a3.x, a3.y, a3.z, a3.w,
                                      a4.x, a4.y, a4.z, a4.w};
                #pragma unroll
                for (int co = 0; co < 4; ++co) {
                    const float4 wv = *(const float4*)&ws[co_l + co][ci][kh * 4];
                    #pragma unroll
                    for (int j = 0; j < 8; ++j) {
                        acc[co][j] = fmaf(xf[2 * j + 0], wv.x, acc[co][j]);
                        acc[co][j] = fmaf(xf[2 * j + 1], wv.y, acc[co][j]);
                        acc[co][j] = fmaf(xf[2 * j + 2], wv.z, acc[co][j]);
                        acc[co][j] = fmaf(xf[2 * j + 3], wv.w, acc[co][j]);
                    }
                }
            }
        }
        __syncthreads();
    }

    // ---- epilogue: ReLU + vectorized store ----
    #pragma unroll
    for (int co = 0; co < 4; ++co) {
        float* __restrict__ yp =
            &y[((b * Cout + co0 + co_l + co) * Ho + oh0 + lho) * Wo + ow0 + lwo];
        float4 r0, r1;
        r0.x = fmaxf(acc[co][0], 0.0f);
        r0.y = fmaxf(acc[co][1], 0.0f);
        r0.z = fmaxf(acc[co][2], 0.0f);
        r0.w = fmaxf(acc[co][3], 0.0f);
        r1.x = fmaxf(acc[co][4], 0.0f);
        r1.y = fmaxf(acc[co][5], 0.0f);
        r1.z = fmaxf(acc[co][6], 0.0f);
        r1.w = fmaxf(acc[co][7], 0.0f);
        *(float4*)yp       = r0;
        *(float4*)(yp + 4) = r1;
    }
}

// codebook row squared norms
__global__ __launch_bounds__(THREADS)
void cnorm_kernel(const float* __restrict__ cb, float* __restrict__ cn) {
    int c = blockIdx.x * THREADS + threadIdx.x;   // 8192 rows
    const float* __restrict__ row = cb + c * 256;
    float s = 0.0f;
    for (int k = 0; k < 256; k += 4) {
        float4 v = *(const float4*)(row + k);
        s = fmaf(v.x, v.x, s);
        s = fmaf(v.y, v.y, s);
        s = fmaf(v.z, v.z, s);
        s = fmaf(v.w, v.w, s);
    }
    cn[c] = s;
}

__global__ __launch_bounds__(THREADS)
void vq_init_kernel(unsigned long long* __restrict__ packed) {
    int i = blockIdx.x * THREADS + threadIdx.x;
    packed[i] = 0xFFFFFFFFFFFFFFFFULL;
}

// ---------------------------------------------------------------------------
// VQ argmin as tiled fp32 GEMM.
// Grid: 256 q-blocks (32 queries each) x 4 code-splits (2048 codes each).
// Block: zt[256k][32q] staged once (z4 NCHW is [k][q]-contiguous).
//        Per 128-code tile: 8 chunks of cl[128c][32k], coalesced stage.
// Thread (qg=t&7, cg=t>>3): 4q x 4c register tile; per k4-step:
//   4 ds_read_b128 from zt (stride-4, conflict-free) +
//   4 ds_read_b128 from cl (2 distinct addrs/wave -> broadcast) + 64 fma.
// acc chains run over k strictly ascending -> bitwise equal to the previous
// passing kernel's distances -> identical argmin. Lexicographic (d, idx)
// min via shfl + LDS partials + packed u64 atomicMin.
// ---------------------------------------------------------------------------
#define VQ_CT 128
#define VQ_KCH 32
__global__ __launch_bounds__(THREADS)
void vq_argmin_kernel(const float* __restrict__ z, const float* __restrict__ cb,
                      const float* __restrict__ cnorm,
                      unsigned long long* __restrict__ packed) {
    __shared__ float zt[256][32];       // [k][q]  32 KB
    __shared__ float cl[VQ_CT][36];     // [c][k-chunk]  18 KB
    __shared__ float pd[4][8][4];       // per-wave partial best d
    __shared__ int   pi[4][8][4];

    const int t  = threadIdx.x;
    const int qg = t & 7;               // 8 query groups x 4 q
    const int cg = t >> 3;              // 32 code groups x 4 c
    const int qblk   = blockIdx.x >> 2;
    const int csplit = blockIdx.x & 3;
    const int q0  = qblk * 32;
    const int b   = q0 >> 8;
    const int hw0 = q0 & 255;

    // ---- stage zt[k][q]: k=0..255, q=0..31 (coalesced float4) ----
    {
        const float* __restrict__ zb = z + (b * 256) * 256 + hw0;
        #pragma unroll
        for (int i = 0; i < 8; ++i) {
            const int k  = (t >> 3) + i * 32;
            const int q4 = (t & 7) * 4;
            *(float4*)&zt[k][q4] = *(const float4*)(zb + k * 256 + q4);
        }
    }

    float bd[4];
    int   bi[4];
    #pragma unroll
    for (int j = 0; j < 4; ++j) { bd[j] = 3.4e38f; bi[j] = 0; }

    const int cbase0 = csplit * 2048;

    #pragma unroll 1
    for (int ct = 0; ct < 2048 / VQ_CT; ++ct) {
        const int cb0 = cbase0 + ct * VQ_CT;

        float acc[4][4];
        #pragma unroll
        for (int iq = 0; iq < 4; ++iq)
            #pragma unroll
            for (int j = 0; j < 4; ++j) acc[iq][j] = 0.0f;

        #pragma unroll 1
        for (int kc = 0; kc < 256 / VQ_KCH; ++kc) {
            __syncthreads();            // protect cl (and zt on first pass)
            // stage cl[c][k]: 128 c x 32 k, 4 float4 per thread, coalesced
            #pragma unroll
            for (int i = 0; i < 4; ++i) {
                const int idx = t + i * THREADS;      // 0..1023
                const int c   = idx >> 3;
                const int m   = idx & 7;
                *(float4*)&cl[c][m * 4] =
                    *(const float4*)(cb + (cb0 + c) * 256 + kc * VQ_KCH + m * 4);
            }
            __syncthreads();

            const int kb = kc * VQ_KCH;
            #pragma unroll
            for (int k4 = 0; k4 < VQ_KCH / 4; ++k4) {
                const int kk = k4 * 4;
                float4 zv0 = *(const float4*)&zt[kb + kk + 0][qg * 4];
                float4 zv1 = *(const float4*)&zt[kb + kk + 1][qg * 4];
                float4 zv2 = *(const float4*)&zt[kb + kk + 2][qg * 4];
                float4 zv3 = *(const float4*)&zt[kb + kk + 3][qg * 4];
                #pragma unroll
                for (int j = 0; j < 4; ++j) {
                    const float4 cv = *(const float4*)&cl[cg * 4 + j][kk];
                    // k ascending within: cv.x (k=kk) ... cv.w (k=kk+3)
                    acc[0][j] = fmaf(zv0.x, cv.x, acc[0][j]);
                    acc[1][j] = fmaf(zv0.y, cv.x, acc[1][j]);
                    acc[2][j] = fmaf(zv0.z, cv.x, acc[2][j]);
                    acc[3][j] = fmaf(zv0.w, cv.x, acc[3][j]);
                    acc[0][j] = fmaf(zv1.x, cv.y, acc[0][j]);
                    acc[1][j] = fmaf(zv1.y, cv.y, acc[1][j]);
                    acc[2][j] = fmaf(zv1.z, cv.y, acc[2][j]);
                    acc[3][j] = fmaf(zv1.w, cv.y, acc[3][j]);
                    acc[0][j] = fmaf(zv2.x, cv.z, acc[0][j]);
                    acc[1][j] = fmaf(zv2.y, cv.z, acc[1][j]);
                    acc[2][j] = fmaf(zv2.z, cv.z, acc[2][j]);
                    acc[3][j] = fmaf(zv2.w, cv.z, acc[3][j]);
                    acc[0][j] = fmaf(zv3.x, cv.w, acc[0][j]);
                    acc[1][j] = fmaf(zv3.y, cv.w, acc[1][j]);
                    acc[2][j] = fmaf(zv3.z, cv.w, acc[2][j]);
                    acc[3][j] = fmaf(zv3.w, cv.w, acc[3][j]);
                }
            }
        }

        // ---- d = ||c||^2 - 2 z.c ; running lexicographic min ----
        #pragma unroll
        for (int j = 0; j < 4; ++j) {
            const int c = cb0 + cg * 4 + j;
            const float cn = cnorm[c];
            #pragma unroll
            for (int iq = 0; iq < 4; ++iq) {
                const float d = fmaf(-2.0f, acc[iq][j], cn);
                if (d < bd[iq]) { bd[iq] = d; bi[iq] = c; }
            }
        }
    }

    // ---- reduce over cg: intra-wave shfl (cg bits 3..5 of lane) ----
    #pragma unroll
    for (int off = 8; off <= 32; off <<= 1) {
        #pragma unroll
        for (int iq = 0; iq < 4; ++iq) {
            const float od = __shfl_xor(bd[iq], off);
            const int   oi = __shfl_xor(bi[iq], off);
            if (od < bd[iq] || (od == bd[iq] && oi < bi[iq])) {
                bd[iq] = od; bi[iq] = oi;
            }
        }
    }
    const int wv = t >> 6;
    if ((t & 63) < 8) {
        #pragma unroll
        for (int iq = 0; iq < 4; ++iq) { pd[wv][qg][iq] = bd[iq]; pi[wv][qg][iq] = bi[iq]; }
    }
    __syncthreads();
    if (t < 32) {
        const int qq = t >> 2;          // qg
        const int iq = t & 3;
        float best = pd[0][qq][iq]; int besti = pi[0][qq][iq];
        #pragma unroll
        for (int w2 = 1; w2 < 4; ++w2) {
            const float d = pd[w2][qq][iq]; const int i2 = pi[w2][qq][iq];
            if (d < best || (d == best && i2 < besti)) { best = d; besti = i2; }
        }
        unsigned int k = __float_as_uint(best);
        k = (k & 0x80000000u) ? ~k : (k | 0x80000000u);
        const unsigned long long pk =
            ((unsigned long long)k << 32) | (unsigned int)besti;
        atomicMin(&packed[q0 + qq * 4 + iq], pk);
    }
}

// Epilogue: out[0:2097152] = codebook[idx] in NCHW; out[2097152:] = (float)idx.
__global__ __launch_bounds__(THREADS)
void gather_kernel(const float* __restrict__ cb,
                   const unsigned long long* __restrict__ packed,
                   float* __restrict__ out) {
    int i = blockIdx.x * THREADS + threadIdx.x;
    if (i < 32 * 256 * 16 * 16) {
        int w = i & 15;
        int h = (i >> 4) & 15;
        int c = (i >> 8) & 255;
        int b = i >> 16;
        int n = (b << 8) | (h << 4) | w;
        int idx = (int)(packed[n] & 0xFFFFFFFFULL);
        out[i] = cb[idx * 256 + c];
    }
    if (i < 8192) {
        int idx = (int)(packed[i] & 0xFFFFFFFFULL);
        out[32 * 256 * 16 * 16 + i] = (float)idx;
    }
}

extern "C" void kernel_launch(void* const* d_in, const int* in_sizes, int n_in,
                              void* d_out, int out_size, void* d_ws, size_t ws_size,
                              hipStream_t stream) {
    const float* x  = (const float*)d_in[0];
    const float* w1 = (const float*)d_in[1];
    const float* b1 = (const float*)d_in[2];
    const float* w2 = (const float*)d_in[3];
    const float* b2 = (const float*)d_in[4];
    const float* w3 = (const float*)d_in[5];
    const float* b3 = (const float*)d_in[6];
    const float* w4 = (const float*)d_in[7];
    const float* b4 = (const float*)d_in[8];
    const float* cb = (const float*)d_in[9];
    float* out = (float*)d_out;

    char* ws = (char*)d_ws;
    // z1: 32*64*128*128 f32 = 134217728 B @ 0
    // z2: 32*128*64*64  f32 =  67108864 B @ 134217728
    // z3: 32*256*32*32  f32 =  33554432 B @ 0          (reuse z1)
    // z4: 32*256*16*16  f32 =   8388608 B @ 134217728  (reuse z2)
    // cnorm: 8192 f32 @ 142606336
    // packed: 8192 u64 @ 0 (reuse z1/z3 region -- dead after conv4)
    float* z1 = (float*)(ws);
    float* z2 = (float*)(ws + 134217728);
    float* z3 = (float*)(ws);
    float* z4 = (float*)(ws + 134217728);
    float* cn = (float*)(ws + 142606336);
    unsigned long long* pk = (unsigned long long*)(ws);

    // conv1: (32,3,256,256) -> (32,64,128,128)   grid: 32 * 1ct * 16ht * 8wt
    conv_tiled_kernel<3, 3><<<32 * 1 * 16 * 8, THREADS, 0, stream>>>(
        x, w1, b1, z1, 32, 64, 256, 256, 1, 16, 8);
    // conv2: -> (32,128,64,64)                   grid: 32 * 2 * 8 * 4
    conv_tiled_kernel<64, 4><<<32 * 2 * 8 * 4, THREADS, 0, stream>>>(
        z1, w2, b2, z2, 32, 128, 128, 128, 2, 8, 4);
    // conv3: -> (32,256,32,32)                   grid: 32 * 4 * 4 * 2
    conv_tiled_kernel<128, 4><<<32 * 4 * 4 * 2, THREADS, 0, stream>>>(
        z2, w3, b3, z3, 32, 256, 64, 64, 4, 4, 2);
    // conv4: -> (32,256,16,16)                   grid: 32 * 4 * 2 * 1
    conv_tiled_kernel<256, 4><<<32 * 4 * 2 * 1, THREADS, 0, stream>>>(
        z3, w4, b4, z4, 32, 256, 32, 32, 4, 2, 1);

    // VQ
    cnorm_kernel<<<8192 / THREADS, THREADS, 0, stream>>>(cb, cn);
    vq_init_kernel<<<8192 / THREADS, THREADS, 0, stream>>>(pk);
    vq_argmin_kernel<<<(8192 / 32) * 4, THREADS, 0, stream>>>(z4, cb, cn, pk);

    // epilogue
    gather_kernel<<<(32 * 256 * 16 * 16) / THREADS, THREADS, 0, stream>>>(cb, pk, out);
}